// Round 8
// baseline (2975.261 us; speedup 1.0000x reference)
//
#include <hip/hip_runtime.h>

// ---------------- ws layout (float offsets) ----------------
#define O_WC     16
#define O_BC     (16 + 8192)
#define O_BIAS   (O_BC + 64)
#define O_BLEND1 16384
#define O_WB     3293184        // packed hi/lo weights (ushort region)
#define O_H0     3702784        // h plane buf0: [1024][512] ushort (hi|lo)
#define O_H1     3964928        // h plane buf1
#define O_X      4227072        // x plane: [1024][256] ushort (hi|lo)
#define O_CNT    4358144        // grid-barrier slots: 101 x 2 ints
#define NEG_INF_V (-1.0e9f)

#define WB_TILE 12288
#define WB_W2   786432
#define NBLK    256

using bf16x8 = __attribute__((ext_vector_type(8))) __bf16;
using f32x4  = __attribute__((ext_vector_type(4))) float;

__device__ __forceinline__ f32x4 mfma16(bf16x8 a, bf16x8 b, f32x4 c) {
  return __builtin_amdgcn_mfma_f32_16x16x32_bf16(a, b, c, 0, 0, 0);
}

__device__ __forceinline__ float b2f(unsigned int u) {
  union { unsigned int i; float f; } x; x.i = u << 16; return x.f;
}
__device__ __forceinline__ unsigned short f2b(float f) {
  union { float f; unsigned int i; } x; x.f = f;
  unsigned int r = x.i + 0x7fffu + ((x.i >> 16) & 1u);
  return (unsigned short)(r >> 16);
}
__device__ __forceinline__ float ldv(const void* p, int b16, long long i) {
  if (b16) return b2f(((const unsigned short*)p)[i]);
  return ((const float*)p)[i];
}
__device__ __forceinline__ float sigm(float x)  { return 1.0f / (1.0f + __expf(-x)); }
__device__ __forceinline__ float tanhx(float x) { return 1.0f - 2.0f / (1.0f + __expf(2.0f * x)); }

__device__ __forceinline__ float bfsel(const uint4& u, int e) {
  unsigned int w = (e < 2) ? u.x : (e < 4) ? u.y : (e < 6) ? u.z : u.w;
  union { unsigned int i; float f; } x;
  x.i = (e & 1) ? (w & 0xffff0000u) : (w << 16);
  return x.f;
}

// custom all-block barrier; all 256 blocks guaranteed resident (grid == #CUs,
// per-block resources fit every CU). slot = 2 ints {count, flag}, zeroed by prep0.
__device__ __forceinline__ void gridbar(int* slot) {
  __syncthreads();
  if (threadIdx.x == 0) {
    int pos = __hip_atomic_fetch_add(slot, 1, __ATOMIC_ACQ_REL,
                                     __HIP_MEMORY_SCOPE_AGENT);
    if (pos == NBLK - 1) {
      __hip_atomic_store(slot + 1, 1, __ATOMIC_RELEASE, __HIP_MEMORY_SCOPE_AGENT);
    } else {
      while (!__hip_atomic_load(slot + 1, __ATOMIC_ACQUIRE,
                                __HIP_MEMORY_SCOPE_AGENT))
        __builtin_amdgcn_s_sleep(8);
    }
  }
  __syncthreads();
}

// ---------------- prep0: dtype detect + bias + bc + zero barrier slots --------
__global__ void prep0(const void* b_enc, const void* b_ih, const void* b_hh,
                      const void* W1, float* ws) {
  __shared__ int anybig;
  int t = threadIdx.x;
  if (t == 0) anybig = 0;
  __syncthreads();
  {
    unsigned short u = ((const unsigned short*)b_enc)[t];
    float f = b2f((unsigned int)u);
    if (!(fabsf(f) <= 1.0f)) atomicOr(&anybig, 1);
  }
  __syncthreads();
  int b16 = anybig ? 0 : 1;
  if (t == 0) ((int*)ws)[0] = b16;
  ((int*)(ws + O_CNT))[t] = 0;                 // 256 ints: 101 barrier slots
  for (int k = t; k < 1024; k += 256)
    ws[O_BIAS + k] = ldv(b_ih, b16, k) + ldv(b_hh, b16, k);
  if (t < 64) {
    float acc = 0.f;
    for (int h = 0; h < 256; ++h)
      acc += ldv(W1, b16, t * 256 + h) * ldv(b_enc, b16, h);
    ws[O_BC + t] = acc;
  }
}

// ---------------- prep1: Wc = W1 @ W_enc ----------------
__global__ void prep1(const void* W_enc, const void* W1, float* ws) {
  int b16 = ((const int*)ws)[0];
  int o = blockIdx.x * 256 + threadIdx.x;
  int w = o >> 7, i = o & 127;
  float acc = 0.f;
  for (int h = 0; h < 256; ++h)
    acc += ldv(W1, b16, w * 256 + h) * ldv(W_enc, b16, h * 128 + i);
  ws[O_WC + o] = acc;
}

// ---------------- wprep: hi/lo decomposition, packed coalesced layout ---------
__global__ __launch_bounds__(256) void wprep(const void* W_ih, const void* W_hh,
                                             const void* W2, float* ws) {
  const int b16 = ((const int*)ws)[0];
  unsigned short* wb = (unsigned short*)(ws + O_WB);
  int i = blockIdx.x * 256 + threadIdx.x;
  {  // W_hh [1024][256]
    int g = i >> 8, k = i & 255;
    int nt = g >> 4, r = g & 15;
    int kc = k >> 5, lane = ((k >> 3) & 3) * 16 + r, e = k & 7;
    float w = ldv(W_hh, b16, i);
    unsigned short hi = f2b(w);
    long long d = (long long)nt * WB_TILE + kc * 512 + lane * 8 + e;
    wb[d] = hi;
    wb[d + 4096] = f2b(w - b2f((unsigned int)hi));
  }
  if (i < 131072) {  // W_ih [1024][128]
    int g = i >> 7, k = i & 127;
    int nt = g >> 4, r = g & 15;
    int kc = k >> 5, lane = ((k >> 3) & 3) * 16 + r, e = k & 7;
    float w = ldv(W_ih, b16, i);
    unsigned short hi = f2b(w);
    long long d = (long long)nt * WB_TILE + 8192 + kc * 512 + lane * 8 + e;
    wb[d] = hi;
    wb[d + 2048] = f2b(w - b2f((unsigned int)hi));
  }
  if (i < 16384) {   // W2 [64][256]
    int g = i >> 8, k = i & 255;
    int ntw = g >> 4, r = g & 15;
    int kc = k >> 5, lane = ((k >> 3) & 3) * 16 + r, e = k & 7;
    float w = ldv(W2, b16, i);
    unsigned short hi = f2b(w);
    long long d = WB_W2 + ntw * 8192 + kc * 512 + lane * 8 + e;
    wb[d] = hi;
    wb[d + 4096] = f2b(w - b2f((unsigned int)hi));
  }
}

// ---------------- blendk: blend1 = targets @ Wc^T + bc ----------------
__global__ __launch_bounds__(256) void blendk(const void* targets, float* ws) {
  __shared__ float tg[6400];
  __shared__ float wc[8192];
  int b16 = ((const int*)ws)[0];
  int t = threadIdx.x, b = blockIdx.x;
  for (int k = t; k < 8192; k += 256) wc[k] = ws[O_WC + k];
  if (b16) {
    const unsigned short* tp = (const unsigned short*)targets + (long long)b * 6400;
    for (int k = t * 8; k < 6400; k += 2048) {
      uint4 u = *(const uint4*)(tp + k);
      #pragma unroll
      for (int e = 0; e < 8; ++e) tg[k + e] = bfsel(u, e);
    }
  } else {
    const float* tp = (const float*)targets + (long long)b * 6400;
    for (int k = t; k < 6400; k += 256) tg[k] = tp[k];
  }
  __syncthreads();
  int w = t & 63, j0 = t >> 6;
  float bcv = ws[O_BC + w];
  for (int j = j0; j < 50; j += 4) {
    float acc = 0.f;
    for (int i0 = 0; i0 < 128; i0 += 8) {
      const float4* q = (const float4*)(wc + w * 128 + i0);
      float4 a = q[0], bb = q[1];
      const float* x = &tg[j * 128 + i0];
      acc += a.x * x[0] + a.y * x[1] + a.z * x[2] + a.w * x[3]
           + bb.x * x[4] + bb.y * x[5] + bb.z * x[6] + bb.w * x[7];
    }
    ws[O_BLEND1 + (b * 50 + j) * 64 + w] = acc + bcv;
  }
}

// ---------------- mainP: persistent gate-split kernel -------------------------
// 256 blocks = 32 batch-groups x 8 gate-groups. Block (BG,GG): 32 batches,
// gate rows {q*256 + GG*32 .. +32 | q=0..3} = 8 tiles, 1 tile/wave; tile weights
// live in 96 VGPRs/wave for all 50 steps. h (hi/lo, double-buffered) and x
// planes in ws; 2 custom grid barriers per step.
__global__ __launch_bounds__(512)
__attribute__((amdgpu_waves_per_eu(2, 2)))
void mainP(const void* targets, const void* h0, const void* c0, const void* vt,
           float* ws, void* outp) {
  __shared__ __align__(16) unsigned short hL[32][520];  // cols 0-255 hi, 256-511 lo
  __shared__ __align__(16) unsigned short xL[32][264];  // cols 0-127 hi, 128-255 lo
  __shared__ float gsh[32][132];
  __shared__ float cT[32][33];
  __shared__ float b2s[4][64];
  __shared__ float outs[4][64];
  __shared__ float bias_s[128];
  __shared__ float vt_s[64];
  __shared__ int   selb[4][64];
  __shared__ int   selx[4];

  const int b16 = ((const int*)ws)[0];
  const int t = threadIdx.x;
  const int BG = blockIdx.x >> 3, GG = blockIdx.x & 7;
  const unsigned short* wb = (const unsigned short*)(ws + O_WB);
  unsigned short* h0p = (unsigned short*)(ws + O_H0);
  unsigned short* h1p = (unsigned short*)(ws + O_H1);
  unsigned short* xP  = (unsigned short*)(ws + O_X);
  int* bar = (int*)(ws + O_CNT);

  const int l  = t & 63, Wv = t >> 6;       // lane, wave (0..7)
  const int lr = l & 15, hc = l >> 4;
  const int nt = (Wv >> 1) * 16 + GG * 2 + (Wv & 1);   // this wave's gate tile

  // ---- persistent weight registers (12 KB -> 96 VGPR/wave) ----
  bf16x8 wH[12], wL[12];
  {
    const unsigned short* tb = wb + (long long)nt * WB_TILE + l * 8;
    #pragma unroll
    for (int kc = 0; kc < 8; ++kc) {
      wH[kc] = *(const bf16x8*)(tb + kc * 512);
      wL[kc] = *(const bf16x8*)(tb + 4096 + kc * 512);
    }
    #pragma unroll
    for (int kc = 0; kc < 4; ++kc) {
      wH[8 + kc] = *(const bf16x8*)(tb + 8192 + kc * 512);
      wL[8 + kc] = *(const bf16x8*)(tb + 10240 + kc * 512);
    }
  }

  // ---- init: bias/vt/selb, h buf0 + x plane + c-state slices ----
  if (t < 128) bias_s[t] = ws[O_BIAS + (t >> 5) * 256 + GG * 32 + (t & 31)];
  if (t < 64) vt_s[t] = ldv(vt, b16, t);
  if (t < 256) selb[t >> 6][t & 63] = 0;
  for (int k = t; k < 1024; k += 512) {      // h0/c0: 32 batches x j-slice
    int p = k >> 5, jj = k & 31;
    int bt = BG * 32 + p, j = GG * 32 + jj;
    float h = ldv(h0, b16, (long long)bt * 256 + j);
    float c = ldv(c0, b16, (long long)bt * 256 + j);
    unsigned short hi = f2b(h);
    h0p[bt * 512 + j]       = hi;
    h0p[bt * 512 + 256 + j] = f2b(h - b2f((unsigned int)hi));
    cT[p][jj] = c;
  }
  for (int k = t; k < 512; k += 512) {       // x = 0 for owned 4 batches
    int p4 = k >> 7, i = k & 127;
    int bt = BG * 32 + GG * 4 + p4;
    xP[bt * 256 + i] = 0; xP[bt * 256 + 128 + i] = 0;
  }
  gridbar(bar + 100 * 2);

  #pragma unroll 1
  for (int step = 0; step < 50; ++step) {
    unsigned short* hRd = (step & 1) ? h1p : h0p;
    unsigned short* hWr = (step & 1) ? h0p : h1p;

    // ---- stage h,x (32 batches) into LDS ----
    for (int k = t; k < 2048; k += 512) {    // h: 32 x 512 ushort
      int row = k >> 6, c8 = (k & 63) * 8;
      *(uint4*)&hL[row][c8] = *(const uint4*)(hRd + (BG * 32 + row) * 512 + c8);
    }
    for (int k = t; k < 1024; k += 512) {    // x: 32 x 256 ushort
      int row = k >> 5, c8 = (k & 31) * 8;
      *(uint4*)&xL[row][c8] = *(const uint4*)(xP + (BG * 32 + row) * 256 + c8);
    }
    __syncthreads();

    // ---- phase A: gates for 32 batches x this wave's 16 gate rows ----
    #pragma unroll
    for (int m = 0; m < 2; ++m) {
      const int row = m * 16 + lr;
      bf16x8 ahh[8], ahl[8], axh[4], axl[4];
      #pragma unroll
      for (int kc = 0; kc < 8; ++kc) {
        ahh[kc] = *(const bf16x8*)&hL[row][kc * 32 + hc * 8];
        ahl[kc] = *(const bf16x8*)&hL[row][256 + kc * 32 + hc * 8];
      }
      #pragma unroll
      for (int kc = 0; kc < 4; ++kc) {
        axh[kc] = *(const bf16x8*)&xL[row][kc * 32 + hc * 8];
        axl[kc] = *(const bf16x8*)&xL[row][128 + kc * 32 + hc * 8];
      }
      f32x4 c0a = {0.f,0.f,0.f,0.f}, c1a = {0.f,0.f,0.f,0.f};
      f32x4 c2a = {0.f,0.f,0.f,0.f}, c3a = {0.f,0.f,0.f,0.f};
      #pragma unroll
      for (int kc = 0; kc < 8; ++kc) {
        c0a = mfma16(ahh[kc], wH[kc], c0a);
        c1a = mfma16(ahh[kc], wL[kc], c1a);
        c2a = mfma16(ahl[kc], wH[kc], c2a);
        c3a = mfma16(ahl[kc], wL[kc], c3a);
      }
      #pragma unroll
      for (int kc = 0; kc < 4; ++kc) {
        c0a = mfma16(axh[kc], wH[8 + kc], c0a);
        c1a = mfma16(axh[kc], wL[8 + kc], c1a);
        c2a = mfma16(axl[kc], wH[8 + kc], c2a);
        c3a = mfma16(axl[kc], wL[8 + kc], c3a);
      }
      f32x4 acc = (c0a + c1a) + (c2a + c3a);
      // D: col=lr (gate within tile), row=hc*4+reg (batch within 16)
      #pragma unroll
      for (int r = 0; r < 4; ++r)
        gsh[m * 16 + hc * 4 + r][Wv * 16 + lr] = acc[r];
    }
    __syncthreads();

    // ---- phase A2: LSTM pointwise on (32 batches x 32 j's); write h planes ----
    for (int k = t; k < 1024; k += 512) {
      int p = k >> 5, jj = k & 31;
      float gi = sigm (gsh[p][jj]      + bias_s[jj]);
      float gf = sigm (gsh[p][32 + jj] + bias_s[32 + jj]);
      float gg = tanhx(gsh[p][64 + jj] + bias_s[64 + jj]);
      float go = sigm (gsh[p][96 + jj] + bias_s[96 + jj]);
      float c = gf * cT[p][jj] + gi * gg;
      cT[p][jj] = c;
      float h = go * tanhx(c);
      unsigned short hi = f2b(h);
      int bt = BG * 32 + p, j = GG * 32 + jj;
      hWr[bt * 512 + j]       = hi;
      hWr[bt * 512 + 256 + j] = f2b(h - b2f((unsigned int)hi));
    }
    gridbar(bar + (step * 2) * 2);           // SYNC1: h complete

    // ---- phase C: owned 4 batches. blend2 via MFMA (waves 0-3) ----
    if (Wv < 4) {
      const int v = Wv;
      bf16x8 A8[8];
      const int bslot = lr & 3;
      const unsigned short* hb =
          hWr + (long long)(BG * 32 + GG * 4 + bslot) * 512 +
          ((lr < 4) ? 0 : 256) + hc * 8;
      #pragma unroll
      for (int kc = 0; kc < 8; ++kc) {
        if (lr < 8) A8[kc] = *(const bf16x8*)(hb + kc * 32);
        else { uint4 zz = {0u,0u,0u,0u}; A8[kc] = *(bf16x8*)&zz; }
      }
      const unsigned short* tb2 = wb + WB_W2 + v * 8192 + l * 8;
      f32x4 cH = {0.f,0.f,0.f,0.f}, cL = {0.f,0.f,0.f,0.f};
      #pragma unroll
      for (int kc = 0; kc < 8; ++kc) {
        cH = mfma16(A8[kc], *(const bf16x8*)(tb2 + kc * 512), cH);
        cL = mfma16(A8[kc], *(const bf16x8*)(tb2 + 4096 + kc * 512), cL);
      }
      f32x4 acc = cH + cL;
      float s0 = acc[0] + __shfl_xor(acc[0], 16, 64);
      float s1 = acc[1] + __shfl_xor(acc[1], 16, 64);
      float s2 = acc[2] + __shfl_xor(acc[2], 16, 64);
      float s3 = acc[3] + __shfl_xor(acc[3], 16, 64);
      if (l < 16) {
        b2s[0][v * 16 + lr] = s0; b2s[1][v * 16 + lr] = s1;
        b2s[2][v * 16 + lr] = s2; b2s[3][v * 16 + lr] = s3;
      }
    }
    __syncthreads();

    // ---- out = vt . tanh(blend1 + blend2), mask (200 rows, 2 thr/row) ----
    if (t < 400) {
      int o = t >> 1, sp = t & 1;
      int pc = o / 50, j = o - pc * 50;
      int bt = BG * 32 + GG * 4 + pc;
      const float* bl = ws + O_BLEND1 + (((long long)bt * 50 + j) * 64) + sp * 32;
      float acc = 0.f;
      #pragma unroll
      for (int v4 = 0; v4 < 8; ++v4) {
        float4 bv = *(const float4*)(bl + v4 * 4);
        int w0 = sp * 32 + v4 * 4;
        acc += vt_s[w0 + 0] * tanhx(bv.x + b2s[pc][w0 + 0]);
        acc += vt_s[w0 + 1] * tanhx(bv.y + b2s[pc][w0 + 1]);
        acc += vt_s[w0 + 2] * tanhx(bv.z + b2s[pc][w0 + 2]);
        acc += vt_s[w0 + 3] * tanhx(bv.w + b2s[pc][w0 + 3]);
      }
      acc += __shfl_xor(acc, 1, 64);
      if (sp == 0) outs[pc][j] = selb[pc][j] ? NEG_INF_V : acc;
    }
    __syncthreads();

    // ---- argmax + softmax + probs (waves 0-3, one owned batch each) ----
    if (Wv < 4) {
      int pc = Wv, lane = l;
      float v = (lane < 50) ? outs[pc][lane] : -3.4e38f;
      int idx = lane;
      #pragma unroll
      for (int msk = 1; msk < 64; msk <<= 1) {
        float ov = __shfl_xor(v, msk, 64);
        int   oi = __shfl_xor(idx, msk, 64);
        if (ov > v || (ov == v && oi < idx)) { v = ov; idx = oi; }
      }
      float e = (lane < 50) ? __expf(outs[pc][lane] - v) : 0.f;
      float ssum = e;
      #pragma unroll
      for (int msk = 1; msk < 64; msk <<= 1) ssum += __shfl_xor(ssum, msk, 64);
      if (lane < 50) {
        float prob = fmaxf(e / ssum, 1e-9f);
        long long o = (long long)(BG * 32 + GG * 4 + pc) * 2500 + step * 50 + lane;
        if (b16) ((unsigned short*)outp)[o] = f2b(prob);
        else     ((float*)outp)[o] = prob;
      }
      if (lane == 0) selx[pc] = idx;
      if (lane == idx) selb[pc][idx] = 1;
    }
    __syncthreads();

    // ---- dec_in gather for owned 4 batches -> x planes ----
    {
      int p4 = t >> 7, i = t & 127;
      int bt = BG * 32 + GG * 4 + p4;
      float xf = ldv(targets, b16, ((long long)bt * 50 + selx[p4]) * 128 + i);
      unsigned short hi = f2b(xf);
      xP[bt * 256 + i]       = hi;
      xP[bt * 256 + 128 + i] = f2b(xf - b2f((unsigned int)hi));
    }
    gridbar(bar + (step * 2 + 1) * 2);       // SYNC2: x (and probs) complete
  }
}

extern "C" void kernel_launch(void* const* d_in, const int* in_sizes, int n_in,
                              void* d_out, int out_size, void* d_ws, size_t ws_size,
                              hipStream_t stream) {
  (void)in_sizes; (void)n_in; (void)out_size; (void)ws_size;
  const void* targets = d_in[0];
  const void* h0      = d_in[1];
  const void* c0      = d_in[2];
  const void* W_enc   = d_in[3];
  const void* b_enc   = d_in[4];
  const void* W_ih    = d_in[5];
  const void* W_hh    = d_in[6];
  const void* b_ih    = d_in[7];
  const void* b_hh    = d_in[8];
  const void* W1      = d_in[9];
  const void* W2      = d_in[10];
  const void* vt      = d_in[11];
  float* ws = (float*)d_ws;

  prep0<<<1, 256, 0, stream>>>(b_enc, b_ih, b_hh, W1, ws);
  prep1<<<32, 256, 0, stream>>>(W_enc, W1, ws);
  wprep<<<1024, 256, 0, stream>>>(W_ih, W_hh, W2, ws);
  blendk<<<1024, 256, 0, stream>>>(targets, ws);
  mainP<<<256, 512, 0, stream>>>(targets, h0, c0, vt, ws, d_out);
}

// Round 9
// 1145.925 us; speedup vs baseline: 2.5964x; 2.5964x over previous
//
#include <hip/hip_runtime.h>

// ---------------- ws layout (float offsets) ----------------
#define O_WC     16
#define O_BC     (16 + 8192)
#define O_BIAS   (O_BC + 64)
#define O_BLEND1 16384
#define O_WB     3293184        // packed hi/lo weights (ushort region), 409600 floats
#define O_XW     4194304        // xw table [1024][50][1024] fp32 (use_xw only)
#define XW_FLOATS 52428800ULL
#define NEG_INF_V (-1.0e9f)

// packed weight region (ushort offsets). Gate tile nt (0..63) stride WB_TILE:
//   [0,4096) hhH kc*512+lane*8+e | [4096,8192) hhL
//   [8192,10240) ihH kc*512+lane*8+e | [10240,12288) ihL
// W2 tile ntw (0..3) at WB_W2 + ntw*8192: [0,4096) hi, [4096,8192) lo.
#define WB_TILE 12288
#define WB_W2   786432

using bf16x8 = __attribute__((ext_vector_type(8))) __bf16;
using f32x4  = __attribute__((ext_vector_type(4))) float;

__device__ __forceinline__ f32x4 mfma16(bf16x8 a, bf16x8 b, f32x4 c) {
  return __builtin_amdgcn_mfma_f32_16x16x32_bf16(a, b, c, 0, 0, 0);
}

__device__ __forceinline__ float b2f(unsigned int u) {
  union { unsigned int i; float f; } x; x.i = u << 16; return x.f;
}
__device__ __forceinline__ unsigned short f2b(float f) {
  union { float f; unsigned int i; } x; x.f = f;
  unsigned int r = x.i + 0x7fffu + ((x.i >> 16) & 1u);
  return (unsigned short)(r >> 16);
}
__device__ __forceinline__ float ldv(const void* p, int b16, long long i) {
  if (b16) return b2f(((const unsigned short*)p)[i]);
  return ((const float*)p)[i];
}
__device__ __forceinline__ float sigm(float x)  { return 1.0f / (1.0f + __expf(-x)); }
__device__ __forceinline__ float tanhx(float x) { return 1.0f - 2.0f / (1.0f + __expf(2.0f * x)); }

__device__ __forceinline__ float bfsel(const uint4& u, int e) {
  unsigned int w = (e < 2) ? u.x : (e < 4) ? u.y : (e < 6) ? u.z : u.w;
  union { unsigned int i; float f; } x;
  x.i = (e & 1) ? (w & 0xffff0000u) : (w << 16);
  return x.f;
}

// ---------------- prep0: dtype detect + bias + bc ----------------
__global__ void prep0(const void* b_enc, const void* b_ih, const void* b_hh,
                      const void* W1, float* ws) {
  __shared__ int anybig;
  int t = threadIdx.x;
  if (t == 0) anybig = 0;
  __syncthreads();
  {
    unsigned short u = ((const unsigned short*)b_enc)[t];
    float f = b2f((unsigned int)u);
    if (!(fabsf(f) <= 1.0f)) atomicOr(&anybig, 1);
  }
  __syncthreads();
  int b16 = anybig ? 0 : 1;
  if (t == 0) ((int*)ws)[0] = b16;
  for (int k = t; k < 1024; k += 256)
    ws[O_BIAS + k] = ldv(b_ih, b16, k) + ldv(b_hh, b16, k);
  if (t < 64) {
    float acc = 0.f;
    for (int h = 0; h < 256; ++h)
      acc += ldv(W1, b16, t * 256 + h) * ldv(b_enc, b16, h);
    ws[O_BC + t] = acc;
  }
}

// ---------------- prep1: Wc = W1 @ W_enc ----------------
__global__ void prep1(const void* W_enc, const void* W1, float* ws) {
  int b16 = ((const int*)ws)[0];
  int o = blockIdx.x * 256 + threadIdx.x;
  int w = o >> 7, i = o & 127;
  float acc = 0.f;
  for (int h = 0; h < 256; ++h)
    acc += ldv(W1, b16, w * 256 + h) * ldv(W_enc, b16, h * 128 + i);
  ws[O_WC + o] = acc;
}

// ---------------- wprep: hi/lo decomposition, packed coalesced layout ---------
__global__ __launch_bounds__(256) void wprep(const void* W_ih, const void* W_hh,
                                             const void* W2, float* ws) {
  const int b16 = ((const int*)ws)[0];
  unsigned short* wb = (unsigned short*)(ws + O_WB);
  int i = blockIdx.x * 256 + threadIdx.x;
  {  // W_hh [1024][256]
    int g = i >> 8, k = i & 255;
    int nt = g >> 4, r = g & 15;
    int kc = k >> 5, lane = ((k >> 3) & 3) * 16 + r, e = k & 7;
    float w = ldv(W_hh, b16, i);
    unsigned short hi = f2b(w);
    long long d = (long long)nt * WB_TILE + kc * 512 + lane * 8 + e;
    wb[d] = hi;
    wb[d + 4096] = f2b(w - b2f((unsigned int)hi));
  }
  if (i < 131072) {  // W_ih [1024][128]
    int g = i >> 7, k = i & 127;
    int nt = g >> 4, r = g & 15;
    int kc = k >> 5, lane = ((k >> 3) & 3) * 16 + r, e = k & 7;
    float w = ldv(W_ih, b16, i);
    unsigned short hi = f2b(w);
    long long d = (long long)nt * WB_TILE + 8192 + kc * 512 + lane * 8 + e;
    wb[d] = hi;
    wb[d + 2048] = f2b(w - b2f((unsigned int)hi));
  }
  if (i < 16384) {   // W2 [64][256]
    int g = i >> 8, k = i & 255;
    int ntw = g >> 4, r = g & 15;
    int kc = k >> 5, lane = ((k >> 3) & 3) * 16 + r, e = k & 7;
    float w = ldv(W2, b16, i);
    unsigned short hi = f2b(w);
    long long d = WB_W2 + ntw * 8192 + kc * 512 + lane * 8 + e;
    wb[d] = hi;
    wb[d + 4096] = f2b(w - b2f((unsigned int)hi));
  }
}

// ---------------- blendk: blend1 = targets @ Wc^T + bc ----------------
__global__ __launch_bounds__(256) void blendk(const void* targets, float* ws) {
  __shared__ float tg[6400];
  __shared__ float wc[8192];
  int b16 = ((const int*)ws)[0];
  int t = threadIdx.x, b = blockIdx.x;
  for (int k = t; k < 8192; k += 256) wc[k] = ws[O_WC + k];
  if (b16) {
    const unsigned short* tp = (const unsigned short*)targets + (long long)b * 6400;
    for (int k = t * 8; k < 6400; k += 2048) {
      uint4 u = *(const uint4*)(tp + k);
      #pragma unroll
      for (int e = 0; e < 8; ++e) tg[k + e] = bfsel(u, e);
    }
  } else {
    const float* tp = (const float*)targets + (long long)b * 6400;
    for (int k = t; k < 6400; k += 256) tg[k] = tp[k];
  }
  __syncthreads();
  int w = t & 63, j0 = t >> 6;
  float bcv = ws[O_BC + w];
  for (int j = j0; j < 50; j += 4) {
    float acc = 0.f;
    for (int i0 = 0; i0 < 128; i0 += 8) {
      const float4* q = (const float4*)(wc + w * 128 + i0);
      float4 a = q[0], bb = q[1];
      const float* x = &tg[j * 128 + i0];
      acc += a.x * x[0] + a.y * x[1] + a.z * x[2] + a.w * x[3]
           + bb.x * x[4] + bb.y * x[5] + bb.z * x[6] + bb.w * x[7];
    }
    ws[O_BLEND1 + (b * 50 + j) * 64 + w] = acc + bcv;
  }
}

// ---------------- xwK: xw[b][j][g] = targets[b,j,:].W_ih[g,:] (hi/lo MFMA) ----
// 256 blocks x 4 batches, 512 thr (8 waves, 8 ih-tiles/wave, weights in regs).
// A rows 0-7 = x_hi of 8 j's, rows 8-15 = x_lo; fold shfl_xor(32).
__global__ __launch_bounds__(512)
__attribute__((amdgpu_waves_per_eu(2, 2)))
void xwK(const void* targets, float* ws) {
  __shared__ __align__(16) unsigned short tgS[4][32][264]; // hi 0-127, lo 128-255
  const int b16 = ((const int*)ws)[0];
  const int t = threadIdx.x;
  const int b0 = blockIdx.x * 4;
  const unsigned short* wb = (const unsigned short*)(ws + O_WB);
  float* xwp = ws + O_XW;
  const int l = t & 63, Wv = t >> 6, lr = l & 15, hc = l >> 4;

  #pragma unroll 1
  for (int half = 0; half < 2; ++half) {
    __syncthreads();
    for (int k = t; k < 4 * 32 * 128; k += 512) {
      int p = k >> 12, jr = (k >> 7) & 31, i = k & 127;
      int j = half * 32 + jr;
      float v = (j < 50) ? ldv(targets, b16, ((long long)(b0 + p) * 50 + j) * 128 + i)
                         : 0.f;
      unsigned short hi = f2b(v);
      tgS[p][jr][i]       = hi;
      tgS[p][jr][128 + i] = f2b(v - b2f((unsigned int)hi));
    }
    __syncthreads();
    const int njg = (half == 0) ? 4 : 3;
    #pragma unroll 1
    for (int ti = 0; ti < 8; ++ti) {
      const int nt = Wv * 8 + ti;
      const unsigned short* tb = wb + (long long)nt * WB_TILE + 8192 + l * 8;
      bf16x8 wih[8];
      #pragma unroll
      for (int kc = 0; kc < 4; ++kc) {
        wih[kc]     = *(const bf16x8*)(tb + kc * 512);
        wih[4 + kc] = *(const bf16x8*)(tb + 2048 + kc * 512);
      }
      #pragma unroll 1
      for (int p = 0; p < 4; ++p) {
        #pragma unroll 1
        for (int jh = 0; jh < njg; ++jh) {
          bf16x8 ax[4];
          const unsigned short* tp =
              &tgS[p][jh * 8 + (lr & 7)][((lr < 8) ? 0 : 128) + hc * 8];
          #pragma unroll
          for (int kc = 0; kc < 4; ++kc) ax[kc] = *(const bf16x8*)(tp + kc * 32);
          f32x4 cH = {0.f,0.f,0.f,0.f}, cL = {0.f,0.f,0.f,0.f};
          #pragma unroll
          for (int kc = 0; kc < 4; ++kc) {
            cH = mfma16(ax[kc], wih[kc], cH);
            cL = mfma16(ax[kc], wih[4 + kc], cL);
          }
          f32x4 acc = cH + cL;
          float s0 = acc[0] + __shfl_xor(acc[0], 32, 64);
          float s1 = acc[1] + __shfl_xor(acc[1], 32, 64);
          float s2 = acc[2] + __shfl_xor(acc[2], 32, 64);
          float s3 = acc[3] + __shfl_xor(acc[3], 32, 64);
          if (l < 32) {
            int jb = half * 32 + jh * 8 + hc * 4;
            long long ro = (long long)(b0 + p) * 50;
            if (jb + 0 < 50) xwp[(ro + jb + 0) * 1024 + nt * 16 + lr] = s0;
            if (jb + 1 < 50) xwp[(ro + jb + 1) * 1024 + nt * 16 + lr] = s1;
            if (jb + 2 < 50) xwp[(ro + jb + 2) * 1024 + nt * 16 + lr] = s2;
            if (jb + 3 < 50) xwp[(ro + jb + 3) * 1024 + nt * 16 + lr] = s3;
          }
        }
      }
    }
  }
}

// ---------------- mainX: 50 steps, 4 batches/block, xw table, 16 waves --------
// A rows 0-3 = h_hi(batch), 4-7 = h_lo, 8-15 zero; 2 chains (W_hi, W_lo) give
// all cross terms; fold shfl_xor(16) -> lanes 0-15 rows = batches (r4-proven).
// grid 256 x 1024 thr = 4 waves/SIMD on all CUs; per-tile 16 loads + 16 MFMAs;
// per-CU weight stream 1.0 MB/step. waves_per_eu(4,4): 128-VGPR cap, live ~115.
__global__ __launch_bounds__(1024)
__attribute__((amdgpu_waves_per_eu(4, 4)))
void mainX(const void* targets, const void* h0, const void* c0, const void* vt,
           float* ws, void* outp) {
  __shared__ __align__(16) unsigned short hS[16][264];  // 0-3 hi, 4-7 lo, 8-15 zero
  __shared__ float cT[4][256];
  __shared__ float gsh[4][1024];
  __shared__ float bias_s[1024];
  __shared__ float b2s[4][64];
  __shared__ float outs[4][64];
  __shared__ float vt_s[64];
  __shared__ int   selidx[4];
  __shared__ int   selb[4][64];

  const int b16 = ((const int*)ws)[0];
  const int t = threadIdx.x;
  const int bbase = blockIdx.x * 4;
  const unsigned short* wb = (const unsigned short*)(ws + O_WB);
  const float* xw = ws + O_XW;

  bias_s[t & 1023] = ws[O_BIAS + (t & 1023)];
  if (t < 64) vt_s[t] = ldv(vt, b16, t);
  if (t < 256) selb[t >> 6][t & 63] = 0;
  if (t < 4) selidx[t] = -1;
  {
    unsigned short* z1 = &hS[0][0];
    for (int k = t; k < 16 * 264; k += 1024) z1[k] = 0;
  }
  __syncthreads();
  if (t < 1024) {
    int p = t >> 8, j = t & 255;
    float h = ldv(h0, b16, (long long)(bbase + p) * 256 + j);
    float c = ldv(c0, b16, (long long)(bbase + p) * 256 + j);
    unsigned short hi = f2b(h);
    hS[p][j]     = hi;
    hS[p + 4][j] = f2b(h - b2f((unsigned int)hi));
    cT[p][j]     = c;
  }
  __syncthreads();

  const int l  = t & 63, Wv = t >> 6;   // lane, wave (0..15)
  const int lr = l & 15, hc = l >> 4;

  #pragma unroll 1
  for (int step = 0; step < 50; ++step) {
    // ---- phase A: gsh[p][g] = h@W_hh^T (4 tiles/wave, 16 loads + 16 MFMAs) ----
    {
      bf16x8 ah[8];
      #pragma unroll
      for (int kc = 0; kc < 8; ++kc)
        ah[kc] = *(const bf16x8*)&hS[lr][kc * 32 + hc * 8];
      #pragma unroll 1
      for (int ti = 0; ti < 4; ++ti) {
        const int nt = Wv * 4 + ti;
        const unsigned short* tb = wb + (long long)nt * WB_TILE + l * 8;
        bf16x8 w[16];
        #pragma unroll
        for (int kc = 0; kc < 8; ++kc) {
          w[kc]     = *(const bf16x8*)(tb + kc * 512);
          w[8 + kc] = *(const bf16x8*)(tb + 4096 + kc * 512);
        }
        f32x4 aH = {0.f,0.f,0.f,0.f}, aL = {0.f,0.f,0.f,0.f};
        #pragma unroll
        for (int kc = 0; kc < 8; ++kc) {
          aH = mfma16(ah[kc], w[kc], aH);
          aL = mfma16(ah[kc], w[8 + kc], aL);
        }
        f32x4 acc = aH + aL;
        // rows 0-3 (hi, lanes 0-15) + rows 4-7 (lo, lanes 16-31)
        float s0 = acc[0] + __shfl_xor(acc[0], 16, 64);
        float s1 = acc[1] + __shfl_xor(acc[1], 16, 64);
        float s2 = acc[2] + __shfl_xor(acc[2], 16, 64);
        float s3 = acc[3] + __shfl_xor(acc[3], 16, 64);
        if (l < 16) {
          const int g = nt * 16 + l;
          gsh[0][g] = s0; gsh[1][g] = s1; gsh[2][g] = s2; gsh[3][g] = s3;
        }
      }
    }
    __syncthreads();

    // ---- phase A2: add xw row + bias, LSTM pointwise; h -> hi/lo rows ----
    {
      int j = t & 255, p = t >> 8;
      float gi = gsh[p][j], gf = gsh[p][256 + j];
      float gg = gsh[p][512 + j], go = gsh[p][768 + j];
      int sv = selidx[p];
      if (sv >= 0) {
        const float* xr = xw + ((long long)(bbase + p) * 50 + sv) * 1024;
        gi += xr[j]; gf += xr[256 + j]; gg += xr[512 + j]; go += xr[768 + j];
      }
      gi = sigm (gi + bias_s[j]);
      gf = sigm (gf + bias_s[256 + j]);
      gg = tanhx(gg + bias_s[512 + j]);
      go = sigm (go + bias_s[768 + j]);
      float c = gf * cT[p][j] + gi * gg;
      cT[p][j] = c;
      float h = go * tanhx(c);
      unsigned short hi = f2b(h);
      hS[p][j]     = hi;
      hS[p + 4][j] = f2b(h - b2f((unsigned int)hi));
    }
    __syncthreads();

    // ---- mini-pass: blend2 = h @ W2^T (waves 0-3, 1 tile each) ----
    if (Wv < 4) {
      bf16x8 bh[8];
      #pragma unroll
      for (int kc = 0; kc < 8; ++kc)
        bh[kc] = *(const bf16x8*)&hS[lr][kc * 32 + hc * 8];
      const unsigned short* tb2 = wb + WB_W2 + Wv * 8192 + l * 8;
      f32x4 cH = {0.f,0.f,0.f,0.f}, cL = {0.f,0.f,0.f,0.f};
      #pragma unroll
      for (int kc = 0; kc < 8; ++kc) {
        cH = mfma16(bh[kc], *(const bf16x8*)(tb2 + kc * 512), cH);
        cL = mfma16(bh[kc], *(const bf16x8*)(tb2 + 4096 + kc * 512), cL);
      }
      f32x4 acc = cH + cL;
      float s0 = acc[0] + __shfl_xor(acc[0], 16, 64);
      float s1 = acc[1] + __shfl_xor(acc[1], 16, 64);
      float s2 = acc[2] + __shfl_xor(acc[2], 16, 64);
      float s3 = acc[3] + __shfl_xor(acc[3], 16, 64);
      if (l < 16) {
        const int g = Wv * 16 + l;
        b2s[0][g] = s0; b2s[1][g] = s1; b2s[2][g] = s2; b2s[3][g] = s3;
      }
    }
    __syncthreads();

    // ---- phase C: out = vt . tanh(blend1 + blend2), mask (200 rows x 4 thr) ----
    if (t < 800) {
      int o = t >> 2, q = t & 3;
      int p = o / 50, j = o - p * 50;
      const float* bl = ws + O_BLEND1 + (((long long)(bbase + p) * 50 + j) * 64) + q * 16;
      float acc = 0.f;
      #pragma unroll
      for (int v4 = 0; v4 < 4; ++v4) {
        float4 bv = *(const float4*)(bl + v4 * 4);
        int w0 = q * 16 + v4 * 4;
        acc += vt_s[w0 + 0] * tanhx(bv.x + b2s[p][w0 + 0]);
        acc += vt_s[w0 + 1] * tanhx(bv.y + b2s[p][w0 + 1]);
        acc += vt_s[w0 + 2] * tanhx(bv.z + b2s[p][w0 + 2]);
        acc += vt_s[w0 + 3] * tanhx(bv.w + b2s[p][w0 + 3]);
      }
      acc += __shfl_xor(acc, 1, 64);
      acc += __shfl_xor(acc, 2, 64);
      if (q == 0) outs[p][j] = selb[p][j] ? NEG_INF_V : acc;
    }
    __syncthreads();

    // ---- argmax + softmax + probs (waves 0-3, one batch each) ----
    if (Wv < 4) {
      int p = Wv, lane = l;
      float v = (lane < 50) ? outs[p][lane] : -3.4e38f;
      int idx = lane;
      #pragma unroll
      for (int msk = 1; msk < 64; msk <<= 1) {
        float ov = __shfl_xor(v, msk, 64);
        int   oi = __shfl_xor(idx, msk, 64);
        if (ov > v || (ov == v && oi < idx)) { v = ov; idx = oi; }
      }
      float e = (lane < 50) ? __expf(outs[p][lane] - v) : 0.f;
      float ssum = e;
      #pragma unroll
      for (int msk = 1; msk < 64; msk <<= 1) ssum += __shfl_xor(ssum, msk, 64);
      if (lane < 50) {
        float prob = fmaxf(e / ssum, 1e-9f);
        long long o = (long long)(bbase + p) * 2500 + step * 50 + lane;
        if (b16) ((unsigned short*)outp)[o] = f2b(prob);
        else     ((float*)outp)[o] = prob;
      }
      if (lane == 0) selidx[p] = idx;
      if (lane == idx) selb[p][idx] = 1;
    }
    __syncthreads();
  }
}

// ---------------- mainK6: fallback (round-6-proven, no xw table) ----------------
__global__ __launch_bounds__(512)
__attribute__((amdgpu_waves_per_eu(2, 2)))
void mainK6(const void* targets, const void* h0, const void* c0, const void* vt,
            float* ws, void* outp) {
  __shared__ __align__(16) unsigned short hS[16][264];
  __shared__ __align__(16) unsigned short xA[16][136];
  __shared__ float cT[8][256];
  __shared__ float gsh[8][1024];
  __shared__ float bias_s[1024];
  __shared__ float b2s[8][64];
  __shared__ float outs[8][64];
  __shared__ float vt_s[64];
  __shared__ int   selidx[8];
  __shared__ int   selb[8][64];

  const int b16 = ((const int*)ws)[0];
  const int t = threadIdx.x;
  const int bbase = blockIdx.x * 8;
  const unsigned short* wb = (const unsigned short*)(ws + O_WB);

  for (int k = t; k < 1024; k += 512) bias_s[k] = ws[O_BIAS + k];
  if (t < 64) vt_s[t] = ldv(vt, b16, t);
  if (t < 512) selb[t >> 6][t & 63] = 0;
  if (t < 8) selidx[t] = -1;
  {
    unsigned short* z1 = &hS[0][0];
    unsigned short* z2 = &xA[0][0];
    for (int k = t; k < 16 * 264; k += 512) z1[k] = 0;
    for (int k = t; k < 16 * 136; k += 512) z2[k] = 0;
  }
  __syncthreads();
  for (int k = t; k < 2048; k += 512) {
    int p = k >> 8, j = k & 255;
    float h = ldv(h0, b16, (long long)(bbase + p) * 256 + j);
    float c = ldv(c0, b16, (long long)(bbase + p) * 256 + j);
    unsigned short hi = f2b(h);
    hS[p][j]     = hi;
    hS[p + 8][j] = f2b(h - b2f((unsigned int)hi));
    cT[p][j]     = c;
  }
  __syncthreads();

  const int l  = t & 63, Wv = t >> 6;
  const int lr = l & 15;

  #pragma unroll 1
  for (int step = 0; step < 50; ++step) {
    {
      bf16x8 ah[8], ax[4];
      #pragma unroll
      for (int kc = 0; kc < 8; ++kc)
        ah[kc] = *(const bf16x8*)&hS[lr][kc * 32 + (l >> 4) * 8];
      #pragma unroll
      for (int kc = 0; kc < 4; ++kc)
        ax[kc] = *(const bf16x8*)&xA[lr][kc * 32 + (l >> 4) * 8];
      #pragma unroll 1
      for (int ti = 0; ti < 8; ++ti) {
        const int nt = Wv * 8 + ti;
        const unsigned short* tb = wb + (long long)nt * WB_TILE + l * 8;
        bf16x8 wH[12], wL[12];
        #pragma unroll
        for (int kc = 0; kc < 8; ++kc) {
          wH[kc] = *(const bf16x8*)(tb + kc * 512);
          wL[kc] = *(const bf16x8*)(tb + 4096 + kc * 512);
        }
        #pragma unroll
        for (int kc = 0; kc < 4; ++kc) {
          wH[8 + kc] = *(const bf16x8*)(tb + 8192 + kc * 512);
          wL[8 + kc] = *(const bf16x8*)(tb + 10240 + kc * 512);
        }
        f32x4 aH = {0.f,0.f,0.f,0.f}, aL = {0.f,0.f,0.f,0.f};
        #pragma unroll
        for (int kc = 0; kc < 8; ++kc) {
          aH = mfma16(ah[kc], wH[kc], aH);
          aL = mfma16(ah[kc], wL[kc], aL);
        }
        #pragma unroll
        for (int kc = 0; kc < 4; ++kc) {
          aH = mfma16(ax[kc], wH[8 + kc], aH);
          aL = mfma16(ax[kc], wL[8 + kc], aL);
        }
        f32x4 acc = aH + aL;
        float s0 = acc[0] + __shfl_xor(acc[0], 32, 64);
        float s1 = acc[1] + __shfl_xor(acc[1], 32, 64);
        float s2 = acc[2] + __shfl_xor(acc[2], 32, 64);
        float s3 = acc[3] + __shfl_xor(acc[3], 32, 64);
        if (l < 32) {
          const int g = nt * 16 + (l & 15), pb = (l >> 4) * 4;
          gsh[pb + 0][g] = s0; gsh[pb + 1][g] = s1;
          gsh[pb + 2][g] = s2; gsh[pb + 3][g] = s3;
        }
      }
    }
    __syncthreads();

    for (int k = t; k < 2048; k += 512) {
      int j = k & 255, p = k >> 8;
      float gi = sigm (gsh[p][j]       + bias_s[j]);
      float gf = sigm (gsh[p][256 + j] + bias_s[256 + j]);
      float gg = tanhx(gsh[p][512 + j] + bias_s[512 + j]);
      float go = sigm (gsh[p][768 + j] + bias_s[768 + j]);
      float c = gf * cT[p][j] + gi * gg;
      cT[p][j] = c;
      float h = go * tanhx(c);
      unsigned short hi = f2b(h);
      hS[p][j]     = hi;
      hS[p + 8][j] = f2b(h - b2f((unsigned int)hi));
    }
    __syncthreads();

    if (Wv < 4) {
      bf16x8 bh[8];
      #pragma unroll
      for (int kc = 0; kc < 8; ++kc)
        bh[kc] = *(const bf16x8*)&hS[lr][kc * 32 + (l >> 4) * 8];
      const unsigned short* tb = wb + WB_W2 + Wv * 8192 + l * 8;
      f32x4 aH = {0.f,0.f,0.f,0.f}, aL = {0.f,0.f,0.f,0.f};
      #pragma unroll
      for (int kc = 0; kc < 8; ++kc) {
        aH = mfma16(bh[kc], *(const bf16x8*)(tb + kc * 512), aH);
        aL = mfma16(bh[kc], *(const bf16x8*)(tb + 4096 + kc * 512), aL);
      }
      f32x4 acc = aH + aL;
      float s0 = acc[0] + __shfl_xor(acc[0], 32, 64);
      float s1 = acc[1] + __shfl_xor(acc[1], 32, 64);
      float s2 = acc[2] + __shfl_xor(acc[2], 32, 64);
      float s3 = acc[3] + __shfl_xor(acc[3], 32, 64);
      if (l < 32) {
        const int g = Wv * 16 + (l & 15), pb = (l >> 4) * 4;
        b2s[pb + 0][g] = s0; b2s[pb + 1][g] = s1;
        b2s[pb + 2][g] = s2; b2s[pb + 3][g] = s3;
      }
    }
    __syncthreads();

    if (t < 400) {
      int p = t / 50, j = t - p * 50;
      const float* bl = ws + O_BLEND1 + (((bbase + p) * 50 + j) * 64);
      float acc = 0.f;
      #pragma unroll
      for (int v4 = 0; v4 < 16; ++v4) {
        float4 bv = *(const float4*)(bl + v4 * 4);
        int w0 = v4 * 4;
        acc += vt_s[w0 + 0] * tanhx(bv.x + b2s[p][w0 + 0]);
        acc += vt_s[w0 + 1] * tanhx(bv.y + b2s[p][w0 + 1]);
        acc += vt_s[w0 + 2] * tanhx(bv.z + b2s[p][w0 + 2]);
        acc += vt_s[w0 + 3] * tanhx(bv.w + b2s[p][w0 + 3]);
      }
      outs[p][j] = selb[p][j] ? NEG_INF_V : acc;
    }
    __syncthreads();

    {
      int p = Wv, lane = l;
      float v = (lane < 50) ? outs[p][lane] : -3.4e38f;
      int idx = lane;
      #pragma unroll
      for (int msk = 1; msk < 64; msk <<= 1) {
        float ov = __shfl_xor(v, msk, 64);
        int   oi = __shfl_xor(idx, msk, 64);
        if (ov > v || (ov == v && oi < idx)) { v = ov; idx = oi; }
      }
      float e = (lane < 50) ? __expf(outs[p][lane] - v) : 0.f;
      float ssum = e;
      #pragma unroll
      for (int msk = 1; msk < 64; msk <<= 1) ssum += __shfl_xor(ssum, msk, 64);
      if (lane < 50) {
        float prob = fmaxf(e / ssum, 1e-9f);
        int o = (bbase + p) * 2500 + step * 50 + lane;
        if (b16) ((unsigned short*)outp)[o] = f2b(prob);
        else     ((float*)outp)[o] = prob;
      }
      if (lane == 0) selidx[p] = idx;
      if (lane == idx) selb[p][idx] = 1;
    }
    __syncthreads();

    for (int k = t; k < 1024; k += 512) {
      int p = k >> 7, i = k & 127;
      float xf = ldv(targets, b16,
                     ((long long)(bbase + p) * 50 + selidx[p]) * 128 + i);
      unsigned short hi = f2b(xf);
      xA[p][i]     = hi;
      xA[p + 8][i] = f2b(xf - b2f((unsigned int)hi));
    }
    __syncthreads();
  }
}

extern "C" void kernel_launch(void* const* d_in, const int* in_sizes, int n_in,
                              void* d_out, int out_size, void* d_ws, size_t ws_size,
                              hipStream_t stream) {
  (void)in_sizes; (void)n_in; (void)out_size;
  const void* targets = d_in[0];
  const void* h0      = d_in[1];
  const void* c0      = d_in[2];
  const void* W_enc   = d_in[3];
  const void* b_enc   = d_in[4];
  const void* W_ih    = d_in[5];
  const void* W_hh    = d_in[6];
  const void* b_ih    = d_in[7];
  const void* b_hh    = d_in[8];
  const void* W1      = d_in[9];
  const void* W2      = d_in[10];
  const void* vt      = d_in[11];
  float* ws = (float*)d_ws;

  int use_xw = (ws_size >= ((size_t)O_XW + (size_t)XW_FLOATS) * 4) ? 1 : 0;

  prep0<<<1, 256, 0, stream>>>(b_enc, b_ih, b_hh, W1, ws);
  prep1<<<32, 256, 0, stream>>>(W_enc, W1, ws);
  wprep<<<1024, 256, 0, stream>>>(W_ih, W_hh, W2, ws);
  blendk<<<1024, 256, 0, stream>>>(targets, ws);
  if (use_xw) {
    xwK<<<256, 512, 0, stream>>>(targets, ws);
    mainX<<<256, 1024, 0, stream>>>(targets, h0, c0, vt, ws, d_out);
  } else {
    mainK6<<<128, 512, 0, stream>>>(targets, h0, c0, vt, ws, d_out);
  }
}